// Round 1
// baseline (620.579 us; speedup 1.0000x reference)
//
#include <hip/hip_runtime.h>
#include <hip/hip_bf16.h>
#include <hip/hip_fp16.h>

// Problem constants (match reference)
constexpr int IMG_ = 256;
constexpr int M_   = 1920;   // N_SHOTS * N_SAMPLES
constexpr int B_   = 64;
constexpr int MI_  = M_ * IMG_;          // 491520 elements per phase table
constexpr int IMG2 = IMG_ * IMG_;        // 65536

typedef _Float16 half8 __attribute__((ext_vector_type(8)));
typedef float    floatx4 __attribute__((ext_vector_type(4)));

// global -> LDS direct copy, 16B per lane; LDS dest is wave-uniform base + lane*16
__device__ __forceinline__ void gll16(const _Float16* g, _Float16* l) {
  __builtin_amdgcn_global_load_lds(
      (const __attribute__((address_space(1))) void*)g,
      (__attribute__((address_space(3))) void*)l, 16, 0, 0);
}

// ---------------------------------------------------------------------------
// Phase tables, natural layout [m][i] (f16): Ax = exp(-2i*pi*kx*g), Ay likewise
// ---------------------------------------------------------------------------
__global__ __launch_bounds__(256) void phase1_k(
    const float* __restrict__ samples,
    _Float16* __restrict__ axh_r, _Float16* __restrict__ axh_i,
    _Float16* __restrict__ ayh_r, _Float16* __restrict__ ayh_i) {
  int idx = blockIdx.x * 256 + threadIdx.x;
  if (idx >= MI_) return;
  int m = idx >> 8;
  int i = idx & 255;
  float g  = (float)i - 128.0f;
  float kx = samples[2 * m + 0];
  float ky = samples[2 * m + 1];
  float sx, cx, sy, cy;
  sincospif(-2.0f * kx * g, &sx, &cx);
  sincospif(-2.0f * ky * g, &sy, &cy);
  axh_r[idx] = (_Float16)cx; axh_i[idx] = (_Float16)sx;
  ayh_r[idx] = (_Float16)cy; ayh_i[idx] = (_Float16)sy;
}

// Transposed, pre-conjugated tables [i][m] (f16) for the adjoint pass.
__global__ __launch_bounds__(256) void phase2_k(
    const float* __restrict__ samples,
    _Float16* __restrict__ axtc_r, _Float16* __restrict__ axtc_i,
    _Float16* __restrict__ aytc_r, _Float16* __restrict__ aytc_i) {
  int m = blockIdx.x * 256 + threadIdx.x;
  if (m >= M_) return;
  int i = blockIdx.y;
  float g  = (float)i - 128.0f;
  float kx = samples[2 * m + 0];
  float ky = samples[2 * m + 1];
  float sx, cx, sy, cy;
  sincospif(-2.0f * kx * g, &sx, &cx);
  sincospif(-2.0f * ky * g, &sy, &cy);
  int o = i * M_ + m;
  axtc_r[o] = (_Float16)cx; axtc_i[o] = (_Float16)(-sx);  // conj(Ax)^T
  aytc_r[o] = (_Float16)cy; aytc_i[o] = (_Float16)(-sy);  // conj(Ay)^T
}

// ---------------------------------------------------------------------------
// X transpose + f16 convert: xth[b][j][i] = x[b][i][j]  (B-operand for fwd)
// ---------------------------------------------------------------------------
__global__ __launch_bounds__(256) void xt_k(
    const float* __restrict__ xr, const float* __restrict__ xi,
    _Float16* __restrict__ xth_r, _Float16* __restrict__ xth_i) {
  __shared__ float tr[32][33], ti[32][33];
  const int t = threadIdx.x;
  const int b = blockIdx.z;
  const int i0 = blockIdx.x * 32, j0 = blockIdx.y * 32;
  const int r = t >> 5, c = t & 31;
#pragma unroll
  for (int k = 0; k < 4; ++k) {
    int row = r + k * 8;
    tr[row][c] = xr[(size_t)b * IMG2 + (i0 + row) * IMG_ + j0 + c];
    ti[row][c] = xi[(size_t)b * IMG2 + (i0 + row) * IMG_ + j0 + c];
  }
  __syncthreads();
#pragma unroll
  for (int k = 0; k < 4; ++k) {
    int row = r + k * 8;
    xth_r[(size_t)b * IMG2 + (j0 + row) * IMG_ + i0 + c] = (_Float16)tr[c][row];
    xth_i[(size_t)b * IMG2 + (j0 + row) * IMG_ + i0 + c] = (_Float16)ti[c][row];
  }
}

// ---------------------------------------------------------------------------
// LDS layout (both GEMM kernels): per tile, [row][32 halfs] = [row][4 chunks
// of 16B], stored at chunk' = chunk ^ ((row>>1)&3).  Verified by hand:
//  - staging: HW lane-linear writes (global_load_lds), trivially conflict-free;
//    swizzle applied on the per-lane GLOBAL source address (rule: both-sides).
//  - ds_read_b128 fragments: each 8-lane group hits all 32 banks exactly once.
// ---------------------------------------------------------------------------

// ---------------------------------------------------------------------------
// Forward NDFT via f16 MFMA + fused Ay-weighted j-reduction + density.
//   kspace[b,m] = sum_j Ay[m,j] * (sum_i Ax[m,i] * X_b[i,j]);  kw = K*density
// Block: 256 thr = 4 waves (2wm x 2wj); block-tile 128m x 128j, jc loop x2.
// Wave-tile 64m x 64j (4x4 of 16x16x32) -> 4 B/lane per MFMA from LDS.
// Grid (15, 64). Double-buffered, 1 barrier per k-step.
// ---------------------------------------------------------------------------
__global__ __launch_bounds__(256, 2) void fwd_k(
    const _Float16* __restrict__ axh_r, const _Float16* __restrict__ axh_i,
    const _Float16* __restrict__ ayh_r, const _Float16* __restrict__ ayh_i,
    const _Float16* __restrict__ xth_r, const _Float16* __restrict__ xth_i,
    const float* __restrict__ density,
    _Float16* __restrict__ kwh_r, _Float16* __restrict__ kwh_i) {
  __shared__ _Float16 lds[2][4][128 * 32];   // 64 KB: {Ar,Ai,Br,Bi} x dbuf

  const int t  = threadIdx.x;
  const int w  = t >> 6;
  const int l  = t & 63;
  const int lr = l & 15;   // A/B frag row within 16-tile; C col
  const int q  = l >> 4;   // k-chunk; C row group
  const int wm = w >> 1;
  const int wj = w & 1;
  const int b  = blockIdx.y;
  const int m0 = blockIdx.x * 128;

  // staging lane constants: lane l -> LDS (row = base + l>>2, chunk' = l&3);
  // global chunk = (l&3) ^ p(row), p(row) = (row>>1)&3 = (l>>3)&3 (bases %16==0)
  const int srow   = l >> 2;
  const int schunk = (l & 3) ^ ((l >> 3) & 3);
  const int gOffH  = srow * IMG_ + schunk * 8;   // halfs (row stride 256 halfs)
  const int ldsWB  = (w * 16) * 32;              // wave-uniform LDS base (halfs)
  // fragment-read swizzle: chunk' = q ^ ((lr>>1)&3)
  const int rc = (q ^ ((lr >> 1) & 3)) << 3;

  const floatx4 z4 = {0.f, 0.f, 0.f, 0.f};
  floatx4 accr[4][4], acci[4][4];
#pragma unroll
  for (int a = 0; a < 4; ++a)
#pragma unroll
    for (int c = 0; c < 4; ++c) { accr[a][c] = z4; acci[a][c] = z4; }
  float kr[4][4] = {}, ki[4][4] = {};

  auto stage = [&](int buf, int s) {
    const int jc = s >> 3, kt = s & 7;
    const int col = kt * 32;
    const size_t offA = (size_t)(m0 + w * 16) * IMG_ + col + gOffH;
    const size_t offB = (size_t)b * IMG2 + (size_t)(jc * 128 + w * 16) * IMG_ + col + gOffH;
    _Float16* L = &lds[buf][0][0];
    gll16(axh_r + offA,             L + 0 * 4096 + ldsWB);
    gll16(axh_r + offA + 64 * IMG_, L + 0 * 4096 + ldsWB + 2048);
    gll16(axh_i + offA,             L + 1 * 4096 + ldsWB);
    gll16(axh_i + offA + 64 * IMG_, L + 1 * 4096 + ldsWB + 2048);
    gll16(xth_r + offB,             L + 2 * 4096 + ldsWB);
    gll16(xth_r + offB + 64 * IMG_, L + 2 * 4096 + ldsWB + 2048);
    gll16(xth_i + offB,             L + 3 * 4096 + ldsWB);
    gll16(xth_i + offB + 64 * IMG_, L + 3 * 4096 + ldsWB + 2048);
  };

  auto compute = [&](int buf) {
    const _Float16* L = &lds[buf][0][0];
    half8 ar[4], ai[4];
#pragma unroll
    for (int mt = 0; mt < 4; ++mt) {
      const int ro = (wm * 64 + mt * 16 + lr) * 32 + rc;
      ar[mt] = *(const half8*)&L[0 * 4096 + ro];
      ai[mt] = *(const half8*)&L[1 * 4096 + ro];
    }
#pragma unroll
    for (int jt = 0; jt < 4; ++jt) {
      const int ro = (wj * 64 + jt * 16 + lr) * 32 + rc;
      half8 br  = *(const half8*)&L[2 * 4096 + ro];
      half8 bi  = *(const half8*)&L[3 * 4096 + ro];
      half8 nbi = -bi;
#pragma unroll
      for (int mt = 0; mt < 4; ++mt) {
        accr[mt][jt] = __builtin_amdgcn_mfma_f32_16x16x32_f16(ar[mt], br,  accr[mt][jt], 0, 0, 0);
        accr[mt][jt] = __builtin_amdgcn_mfma_f32_16x16x32_f16(ai[mt], nbi, accr[mt][jt], 0, 0, 0);
        acci[mt][jt] = __builtin_amdgcn_mfma_f32_16x16x32_f16(ar[mt], bi,  acci[mt][jt], 0, 0, 0);
        acci[mt][jt] = __builtin_amdgcn_mfma_f32_16x16x32_f16(ai[mt], br,  acci[mt][jt], 0, 0, 0);
      }
    }
  };

  // Epilogue per jc: kacc[m] += sum_j Ay[m,j]*T[m,j]  (C: col=lr -> j, row=q*4+reg -> m)
  auto epilogue = [&](int jc) {
#pragma unroll
    for (int mt = 0; mt < 4; ++mt)
#pragma unroll
      for (int jt = 0; jt < 4; ++jt) {
        const int j = jc * 128 + wj * 64 + jt * 16 + lr;
#pragma unroll
        for (int reg = 0; reg < 4; ++reg) {
          const int m = m0 + wm * 64 + mt * 16 + q * 4 + reg;
          const float yr = (float)ayh_r[m * IMG_ + j];
          const float yi = (float)ayh_i[m * IMG_ + j];
          const float tr = accr[mt][jt][reg], ti = acci[mt][jt][reg];
          kr[mt][reg] = fmaf(yr, tr, fmaf(-yi, ti, kr[mt][reg]));
          ki[mt][reg] = fmaf(yr, ti, fmaf(yi, tr, ki[mt][reg]));
        }
        accr[mt][jt] = z4;
        acci[mt][jt] = z4;
      }
  };

  stage(0, 0);
  __syncthreads();               // implicit vmcnt(0) drains global_load_lds
  for (int s = 0; s < 16; ++s) {
    const int buf = s & 1;
    if (s < 15) stage(buf ^ 1, s + 1);   // overlap next-tile loads with MFMA
    compute(buf);
    if (s == 7)  epilogue(0);
    if (s == 15) epilogue(1);
    __syncthreads();
  }

  // reduce over the 16 j-lanes of each row group
#pragma unroll
  for (int mt = 0; mt < 4; ++mt)
#pragma unroll
    for (int reg = 0; reg < 4; ++reg)
#pragma unroll
      for (int off = 1; off < 16; off <<= 1) {
        kr[mt][reg] += __shfl_xor(kr[mt][reg], off);
        ki[mt][reg] += __shfl_xor(ki[mt][reg], off);
      }

  // cross-wave (wj) combine via LDS scratch (reuse staging LDS, free after barrier)
  float2* scr = (float2*)&lds[0][0][0];
  if (lr == 0) {
#pragma unroll
    for (int mt = 0; mt < 4; ++mt)
#pragma unroll
      for (int reg = 0; reg < 4; ++reg)
        scr[wj * 128 + wm * 64 + mt * 16 + q * 4 + reg] =
            make_float2(kr[mt][reg], ki[mt][reg]);
  }
  __syncthreads();
  if (t < 128) {
    const int m = m0 + t;
    const float2 p0 = scr[t], p1 = scr[128 + t];
    const float d = density[m];
    kwh_r[b * M_ + m] = (_Float16)((p0.x + p1.x) * d);
    kwh_i[b * M_ + m] = (_Float16)((p0.y + p1.y) * d);
  }
}

// ---------------------------------------------------------------------------
// Adjoint NDFT via f16 MFMA:
//   out[b,i,j] = (1/IMG^2) sum_m conj(Ax)[m,i] * kw[b,m] * conj(Ay)[m,j]
// Block: 256 thr = 4 waves (2wi x 2wj); block-tile 128i x 128j; K = 1920 m.
// A = axtc (pre-conj [i][m]) via global_load_lds; W = kw*conj(Ay) computed in
// regs (loads issued before compute, written after) into swizzled LDS.
// Grid (2, 2, 64) = 256 blocks. Double-buffered, 1 barrier per k-step.
// ---------------------------------------------------------------------------
__global__ __launch_bounds__(256, 2) void adj_k(
    const _Float16* __restrict__ axtc_r, const _Float16* __restrict__ axtc_i,
    const _Float16* __restrict__ aytc_r, const _Float16* __restrict__ aytc_i,
    const _Float16* __restrict__ kwh_r, const _Float16* __restrict__ kwh_i,
    float* __restrict__ out) {
  __shared__ _Float16 lds[2][4][128 * 32];   // 64 KB: {Ar,Ai,Wr,Wi} x dbuf

  const int t  = threadIdx.x;
  const int w  = t >> 6;
  const int l  = t & 63;
  const int lr = l & 15;
  const int q  = l >> 4;
  const int wi = w >> 1;
  const int wj = w & 1;
  const int b  = blockIdx.z;
  const int i0 = blockIdx.x * 128;
  const int j0 = blockIdx.y * 128;

  const int srow   = l >> 2;
  const int schunk = (l & 3) ^ ((l >> 3) & 3);
  const int gOffH  = srow * M_ + schunk * 8;   // A row stride = 1920 halfs
  const int ldsWB  = (w * 16) * 32;
  const int rc = (q ^ ((lr >> 1) & 3)) << 3;

  // W staging: thread -> (j-row = t>>1, m-half = t&1); swizzled b128 writes
  const int wrow = t >> 1;
  const int wh   = t & 1;
  const int wp   = (wrow >> 1) & 3;
  const int wc0  = (((2 * wh + 0) ^ wp) << 3);
  const int wc1  = (((2 * wh + 1) ^ wp) << 3);

  const floatx4 z4 = {0.f, 0.f, 0.f, 0.f};
  floatx4 accr[4][4], acci[4][4];
#pragma unroll
  for (int a = 0; a < 4; ++a)
#pragma unroll
    for (int c = 0; c < 4; ++c) { accr[a][c] = z4; acci[a][c] = z4; }

  uint4 Yr0, Yr1, Yi0, Yi1, Cr0, Cr1, Ci0, Ci1;

  auto stageA = [&](int buf, int s) {
    const int mc = s * 32;
    const size_t off = (size_t)(i0 + w * 16) * M_ + mc + gOffH;
    _Float16* L = &lds[buf][0][0];
    gll16(axtc_r + off,           L + 0 * 4096 + ldsWB);
    gll16(axtc_r + off + 64 * M_, L + 0 * 4096 + ldsWB + 2048);
    gll16(axtc_i + off,           L + 1 * 4096 + ldsWB);
    gll16(axtc_i + off + 64 * M_, L + 1 * 4096 + ldsWB + 2048);
  };

  auto loadW = [&](int s) {   // issue early; consumed by writeW after compute
    const int mc = s * 32 + wh * 16;
    const size_t oy = (size_t)(j0 + wrow) * M_ + mc;
    const size_t oc = (size_t)b * M_ + mc;
    Yr0 = *(const uint4*)&aytc_r[oy];  Yr1 = *(const uint4*)&aytc_r[oy + 8];
    Yi0 = *(const uint4*)&aytc_i[oy];  Yi1 = *(const uint4*)&aytc_i[oy + 8];
    Cr0 = *(const uint4*)&kwh_r[oc];   Cr1 = *(const uint4*)&kwh_r[oc + 8];
    Ci0 = *(const uint4*)&kwh_i[oc];   Ci1 = *(const uint4*)&kwh_i[oc + 8];
  };

  auto writeW = [&](int buf) {
    __half2 Wr0[4], Wi0[4], Wr1[4], Wi1[4];
    {
      const __half2* yr = (const __half2*)&Yr0; const __half2* yi = (const __half2*)&Yi0;
      const __half2* cr = (const __half2*)&Cr0; const __half2* ci = (const __half2*)&Ci0;
#pragma unroll
      for (int e = 0; e < 4; ++e) {
        Wr0[e] = __hsub2(__hmul2(cr[e], yr[e]), __hmul2(ci[e], yi[e]));
        Wi0[e] = __hfma2(cr[e], yi[e], __hmul2(ci[e], yr[e]));
      }
    }
    {
      const __half2* yr = (const __half2*)&Yr1; const __half2* yi = (const __half2*)&Yi1;
      const __half2* cr = (const __half2*)&Cr1; const __half2* ci = (const __half2*)&Ci1;
#pragma unroll
      for (int e = 0; e < 4; ++e) {
        Wr1[e] = __hsub2(__hmul2(cr[e], yr[e]), __hmul2(ci[e], yi[e]));
        Wi1[e] = __hfma2(cr[e], yi[e], __hmul2(ci[e], yr[e]));
      }
    }
    _Float16* Lr = &lds[buf][2][0];
    _Float16* Li = &lds[buf][3][0];
    const int rb = wrow * 32;
    *(uint4*)&Lr[rb + wc0] = *(const uint4*)&Wr0[0];
    *(uint4*)&Lr[rb + wc1] = *(const uint4*)&Wr1[0];
    *(uint4*)&Li[rb + wc0] = *(const uint4*)&Wi0[0];
    *(uint4*)&Li[rb + wc1] = *(const uint4*)&Wi1[0];
  };

  auto compute = [&](int buf) {
    const _Float16* L = &lds[buf][0][0];
    half8 ar[4], ai[4];
#pragma unroll
    for (int mt = 0; mt < 4; ++mt) {
      const int ro = (wi * 64 + mt * 16 + lr) * 32 + rc;
      ar[mt] = *(const half8*)&L[0 * 4096 + ro];
      ai[mt] = *(const half8*)&L[1 * 4096 + ro];
    }
#pragma unroll
    for (int jt = 0; jt < 4; ++jt) {
      const int ro = (wj * 64 + jt * 16 + lr) * 32 + rc;
      half8 br  = *(const half8*)&L[2 * 4096 + ro];
      half8 bi  = *(const half8*)&L[3 * 4096 + ro];
      half8 nbi = -bi;
#pragma unroll
      for (int mt = 0; mt < 4; ++mt) {
        accr[mt][jt] = __builtin_amdgcn_mfma_f32_16x16x32_f16(ar[mt], br,  accr[mt][jt], 0, 0, 0);
        accr[mt][jt] = __builtin_amdgcn_mfma_f32_16x16x32_f16(ai[mt], nbi, accr[mt][jt], 0, 0, 0);
        acci[mt][jt] = __builtin_amdgcn_mfma_f32_16x16x32_f16(ar[mt], bi,  acci[mt][jt], 0, 0, 0);
        acci[mt][jt] = __builtin_amdgcn_mfma_f32_16x16x32_f16(ai[mt], br,  acci[mt][jt], 0, 0, 0);
      }
    }
  };

  loadW(0);
  stageA(0, 0);
  writeW(0);
  __syncthreads();
  for (int s = 0; s < 60; ++s) {
    const int buf = s & 1;
    if (s < 59) { stageA(buf ^ 1, s + 1); loadW(s + 1); }
    compute(buf);
    if (s < 59) writeW(buf ^ 1);
    __syncthreads();
  }

  const float sc = 1.0f / (float)IMG2;
#pragma unroll
  for (int mt = 0; mt < 4; ++mt)
#pragma unroll
    for (int jt = 0; jt < 4; ++jt) {
      const int jg = j0 + wj * 64 + jt * 16 + lr;
#pragma unroll
      for (int reg = 0; reg < 4; ++reg) {
        const int ig = i0 + wi * 64 + mt * 16 + q * 4 + reg;
        float2 v = make_float2(accr[mt][jt][reg] * sc, acci[mt][jt][reg] * sc);
        *(float2*)&out[((size_t)(b * IMG_ + ig) * IMG_ + jg) * 2] = v;
      }
    }
}

// ---------------------------------------------------------------------------
// Launch
// ---------------------------------------------------------------------------
extern "C" void kernel_launch(void* const* d_in, const int* in_sizes, int n_in,
                              void* d_out, int out_size, void* d_ws, size_t ws_size,
                              hipStream_t stream) {
  (void)in_sizes; (void)n_in; (void)out_size; (void)ws_size;

  const float* xr      = (const float*)d_in[0];
  const float* xi      = (const float*)d_in[1];
  const float* samples = (const float*)d_in[2];
  const float* density = (const float*)d_in[3];
  float* out = (float*)d_out;

  // ws: 10 f16 arrays, 8.36 MB total
  _Float16* f = (_Float16*)d_ws;
  _Float16* axh_r  = f + 0 * MI_;
  _Float16* axh_i  = f + 1 * MI_;
  _Float16* ayh_r  = f + 2 * MI_;
  _Float16* ayh_i  = f + 3 * MI_;
  _Float16* axtc_r = f + 4 * MI_;
  _Float16* axtc_i = f + 5 * MI_;
  _Float16* aytc_r = f + 6 * MI_;
  _Float16* aytc_i = f + 7 * MI_;
  _Float16* kwh_r  = f + 8 * MI_;
  _Float16* kwh_i  = kwh_r + B_ * M_;

  // X^T (f16) parked in d_out; fully consumed by fwd_k before adj_k overwrites.
  _Float16* xth_r = (_Float16*)d_out;
  _Float16* xth_i = xth_r + (size_t)B_ * IMG2;

  phase1_k<<<(MI_ + 255) / 256, 256, 0, stream>>>(samples, axh_r, axh_i, ayh_r, ayh_i);
  phase2_k<<<dim3(8, IMG_), 256, 0, stream>>>(samples, axtc_r, axtc_i, aytc_r, aytc_i);
  xt_k<<<dim3(8, 8, B_), 256, 0, stream>>>(xr, xi, xth_r, xth_i);
  fwd_k<<<dim3(M_ / 128, B_), 256, 0, stream>>>(axh_r, axh_i, ayh_r, ayh_i,
                                                xth_r, xth_i, density, kwh_r, kwh_i);
  adj_k<<<dim3(2, 2, B_), 256, 0, stream>>>(axtc_r, axtc_i, aytc_r, aytc_i,
                                            kwh_r, kwh_i, out);
}

// Round 2
// 341.213 us; speedup vs baseline: 1.8187x; 1.8187x over previous
//
#include <hip/hip_runtime.h>
#include <hip/hip_bf16.h>
#include <hip/hip_fp16.h>

// Problem constants (match reference)
constexpr int IMG_ = 256;
constexpr int M_   = 1920;   // N_SHOTS * N_SAMPLES
constexpr int B_   = 64;
constexpr int MI_  = M_ * IMG_;          // 491520 elements per phase table
constexpr int IMG2 = IMG_ * IMG_;        // 65536

typedef _Float16 half8 __attribute__((ext_vector_type(8)));
typedef float    floatx4 __attribute__((ext_vector_type(4)));

// global -> LDS direct copy, 16B per lane; LDS dest is wave-uniform base + lane*16
__device__ __forceinline__ void gll16(const _Float16* g, _Float16* l) {
  __builtin_amdgcn_global_load_lds(
      (const __attribute__((address_space(1))) void*)g,
      (__attribute__((address_space(3))) void*)l, 16, 0, 0);
}

// ---------------------------------------------------------------------------
// Phase tables, natural layout [m][i] (f16): Ax = exp(-2i*pi*kx*g), Ay likewise
// ---------------------------------------------------------------------------
__global__ __launch_bounds__(256) void phase1_k(
    const float* __restrict__ samples,
    _Float16* __restrict__ axh_r, _Float16* __restrict__ axh_i,
    _Float16* __restrict__ ayh_r, _Float16* __restrict__ ayh_i) {
  int idx = blockIdx.x * 256 + threadIdx.x;
  if (idx >= MI_) return;
  int m = idx >> 8;
  int i = idx & 255;
  float g  = (float)i - 128.0f;
  float kx = samples[2 * m + 0];
  float ky = samples[2 * m + 1];
  float sx, cx, sy, cy;
  sincospif(-2.0f * kx * g, &sx, &cx);
  sincospif(-2.0f * ky * g, &sy, &cy);
  axh_r[idx] = (_Float16)cx; axh_i[idx] = (_Float16)sx;
  ayh_r[idx] = (_Float16)cy; ayh_i[idx] = (_Float16)sy;
}

// Transposed, pre-conjugated tables [i][m] (f16) for the adjoint pass.
__global__ __launch_bounds__(256) void phase2_k(
    const float* __restrict__ samples,
    _Float16* __restrict__ axtc_r, _Float16* __restrict__ axtc_i,
    _Float16* __restrict__ aytc_r, _Float16* __restrict__ aytc_i) {
  int m = blockIdx.x * 256 + threadIdx.x;
  if (m >= M_) return;
  int i = blockIdx.y;
  float g  = (float)i - 128.0f;
  float kx = samples[2 * m + 0];
  float ky = samples[2 * m + 1];
  float sx, cx, sy, cy;
  sincospif(-2.0f * kx * g, &sx, &cx);
  sincospif(-2.0f * ky * g, &sy, &cy);
  int o = i * M_ + m;
  axtc_r[o] = (_Float16)cx; axtc_i[o] = (_Float16)(-sx);  // conj(Ax)^T
  aytc_r[o] = (_Float16)cy; aytc_i[o] = (_Float16)(-sy);  // conj(Ay)^T
}

// ---------------------------------------------------------------------------
// X transpose + f16 convert: xth[b][j][i] = x[b][i][j]  (B-operand for fwd)
// ---------------------------------------------------------------------------
__global__ __launch_bounds__(256) void xt_k(
    const float* __restrict__ xr, const float* __restrict__ xi,
    _Float16* __restrict__ xth_r, _Float16* __restrict__ xth_i) {
  __shared__ float tr[32][33], ti[32][33];
  const int t = threadIdx.x;
  const int b = blockIdx.z;
  const int i0 = blockIdx.x * 32, j0 = blockIdx.y * 32;
  const int r = t >> 5, c = t & 31;
#pragma unroll
  for (int k = 0; k < 4; ++k) {
    int row = r + k * 8;
    tr[row][c] = xr[(size_t)b * IMG2 + (i0 + row) * IMG_ + j0 + c];
    ti[row][c] = xi[(size_t)b * IMG2 + (i0 + row) * IMG_ + j0 + c];
  }
  __syncthreads();
#pragma unroll
  for (int k = 0; k < 4; ++k) {
    int row = r + k * 8;
    xth_r[(size_t)b * IMG2 + (j0 + row) * IMG_ + i0 + c] = (_Float16)tr[c][row];
    xth_i[(size_t)b * IMG2 + (j0 + row) * IMG_ + i0 + c] = (_Float16)ti[c][row];
  }
}

// ---------------------------------------------------------------------------
// LDS layout (both GEMM kernels), per 32-half (64B) row of 4 16B chunks:
// physical chunk p of row r holds logical chunk p ^ ((r>>1)&3).
//  - staging via global_load_lds: HW writes lane-linear (lane l -> row l>>2,
//    phys chunk l&3); lane fetches global logical chunk (l&3)^((l>>3)&3).
//  - ds_read_b128 frags read phys chunk q ^ ((lr>>1)&3): zero bank conflicts
//    (measured round 1: SQ_LDS_BANK_CONFLICT = 0).
// Regions (halfs): A_r 0..2048, A_i 2048..4096, B_r 4096..8192, B_i 8192..12288
// per buffer (24 KB); x2 double-buffer = 48 KB -> 3 blocks/CU.
// ---------------------------------------------------------------------------

// ---------------------------------------------------------------------------
// Forward NDFT via f16 MFMA + fused Ay-weighted j-reduction + density.
//   kspace[b,m] = sum_j Ay[m,j] * (sum_i Ax[m,i] * X_b[i,j]);  kw = K*density
// Block: 256 thr = 4 waves; block tile 64m x 128j (wave w owns j-slice w*32,
// all waves share the 64 m rows); jc in {0,1} covers j 0..255.
// Wave tile 64m x 32j: acc = 4x2x2x4 = 64 VGPR (register-budget-safe).
// Grid (30, 64). Double-buffered, 1 barrier per k-step, s-loop fully unrolled.
// ---------------------------------------------------------------------------
__global__ __launch_bounds__(256, 3) void fwd_k(
    const _Float16* __restrict__ axh_r, const _Float16* __restrict__ axh_i,
    const _Float16* __restrict__ ayh_r, const _Float16* __restrict__ ayh_i,
    const _Float16* __restrict__ xth_r, const _Float16* __restrict__ xth_i,
    const float* __restrict__ density,
    _Float16* __restrict__ kwh_r, _Float16* __restrict__ kwh_i) {
  __shared__ _Float16 lds[2][12288];   // 48 KB

  const int t  = threadIdx.x;
  const int w  = t >> 6;
  const int l  = t & 63;
  const int lr = l & 15;   // frag row within 16-tile; C col (j)
  const int q  = l >> 4;   // k-chunk; C row group (m)
  const int b  = blockIdx.y;
  const int m0 = blockIdx.x * 64;

  const int srow   = l >> 2;                      // staging row within 16
  const int schunk = (l & 3) ^ ((l >> 3) & 3);    // pre-swizzled global chunk
  const int gA     = srow * IMG_ + schunk * 8;    // halfs
  const int rc     = (q ^ ((lr >> 1) & 3)) << 3;  // frag-read swizzled chunk

  const floatx4 z4 = {0.f, 0.f, 0.f, 0.f};
  floatx4 accr[4][2], acci[4][2];
#pragma unroll
  for (int mt = 0; mt < 4; ++mt)
#pragma unroll
    for (int jt = 0; jt < 2; ++jt) { accr[mt][jt] = z4; acci[mt][jt] = z4; }
  float kr[4][4] = {}, ki[4][4] = {};

  auto stage = [&](int buf, int s) {
    const int jc  = s >> 3, kt = s & 7;
    const int col = kt * 32;
    _Float16* L = lds[buf];
    const size_t offA = (size_t)(m0 + w * 16) * IMG_ + col + gA;
    gll16(axh_r + offA, L + 0    + w * 512);
    gll16(axh_i + offA, L + 2048 + w * 512);
    const size_t offB = (size_t)b * IMG2 + (size_t)(jc * 128 + w * 32) * IMG_ + col + gA;
    gll16(xth_r + offB,             L + 4096 + w * 1024);
    gll16(xth_r + offB + 16 * IMG_, L + 4096 + w * 1024 + 512);
    gll16(xth_i + offB,             L + 8192 + w * 1024);
    gll16(xth_i + offB + 16 * IMG_, L + 8192 + w * 1024 + 512);
  };

  auto compute = [&](int buf) {
    const _Float16* L = lds[buf];
    half8 br[2], bi[2], nbi[2];
#pragma unroll
    for (int jt = 0; jt < 2; ++jt) {
      const int ro = (w * 32 + jt * 16 + lr) * 32 + rc;
      br[jt]  = *(const half8*)&L[4096 + ro];
      bi[jt]  = *(const half8*)&L[8192 + ro];
      nbi[jt] = -bi[jt];
    }
#pragma unroll
    for (int mt = 0; mt < 4; ++mt) {
      const int ro = (mt * 16 + lr) * 32 + rc;
      half8 ar = *(const half8*)&L[0 + ro];
      half8 ai = *(const half8*)&L[2048 + ro];
#pragma unroll
      for (int jt = 0; jt < 2; ++jt) {
        accr[mt][jt] = __builtin_amdgcn_mfma_f32_16x16x32_f16(ar, br[jt],  accr[mt][jt], 0, 0, 0);
        accr[mt][jt] = __builtin_amdgcn_mfma_f32_16x16x32_f16(ai, nbi[jt], accr[mt][jt], 0, 0, 0);
        acci[mt][jt] = __builtin_amdgcn_mfma_f32_16x16x32_f16(ar, bi[jt],  acci[mt][jt], 0, 0, 0);
        acci[mt][jt] = __builtin_amdgcn_mfma_f32_16x16x32_f16(ai, br[jt],  acci[mt][jt], 0, 0, 0);
      }
    }
  };

  // kacc[m] += sum_j Ay[m,j]*T[m,j]  (C layout: col=lr -> j, row=q*4+reg -> m)
  auto epilogue = [&](int jc) {
#pragma unroll
    for (int mt = 0; mt < 4; ++mt)
#pragma unroll
      for (int jt = 0; jt < 2; ++jt) {
        const int j = jc * 128 + w * 32 + jt * 16 + lr;
#pragma unroll
        for (int reg = 0; reg < 4; ++reg) {
          const int m = m0 + mt * 16 + q * 4 + reg;
          const float yr = (float)ayh_r[m * IMG_ + j];
          const float yi = (float)ayh_i[m * IMG_ + j];
          const float tr = accr[mt][jt][reg], ti = acci[mt][jt][reg];
          kr[mt][reg] = fmaf(yr, tr, fmaf(-yi, ti, kr[mt][reg]));
          ki[mt][reg] = fmaf(yr, ti, fmaf(yi, tr, ki[mt][reg]));
        }
        accr[mt][jt] = z4;
        acci[mt][jt] = z4;
      }
  };

  stage(0, 0);
  __syncthreads();               // implicit vmcnt(0) drains global_load_lds
#pragma unroll
  for (int s = 0; s < 16; ++s) {
    const int buf = s & 1;
    if (s < 15) stage(buf ^ 1, s + 1);   // next-tile loads overlap MFMA
    compute(buf);
    if (s == 7) epilogue(0);
    __syncthreads();
  }
  epilogue(1);   // register-only; no barrier needed

  // reduce over the 16 j-lanes of each row group
#pragma unroll
  for (int mt = 0; mt < 4; ++mt)
#pragma unroll
    for (int reg = 0; reg < 4; ++reg)
#pragma unroll
      for (int off = 1; off < 16; off <<= 1) {
        kr[mt][reg] += __shfl_xor(kr[mt][reg], off);
        ki[mt][reg] += __shfl_xor(ki[mt][reg], off);
      }

  // cross-wave combine (4 j-slices) via LDS scratch
  float2* scr = (float2*)&lds[0][0];
  if (lr == 0) {
#pragma unroll
    for (int mt = 0; mt < 4; ++mt)
#pragma unroll
      for (int reg = 0; reg < 4; ++reg)
        scr[w * 64 + mt * 16 + q * 4 + reg] = make_float2(kr[mt][reg], ki[mt][reg]);
  }
  __syncthreads();
  if (t < 64) {
    float sr = 0.f, si = 0.f;
#pragma unroll
    for (int ww = 0; ww < 4; ++ww) {
      const float2 p = scr[ww * 64 + t];
      sr += p.x; si += p.y;
    }
    const int m = m0 + t;
    const float d = density[m];
    kwh_r[b * M_ + m] = (_Float16)(sr * d);
    kwh_i[b * M_ + m] = (_Float16)(si * d);
  }
}

// ---------------------------------------------------------------------------
// Adjoint NDFT via f16 MFMA:
//   out[b,i,j] = (1/IMG^2) sum_m conj(Ax)[m,i] * kw[b,m] * conj(Ay)[m,j]
// Block: 256 thr = 4 waves; block tile 64i x 128j (wave w owns j-slice w*32);
// wave tile 64i x 32j -> acc 64 VGPR. K = 1920 m, 60 steps, double-buffered.
// A = axtc (pre-conj [i][m]) via global_load_lds; W = kw*conj(Ay) computed in
// regs (loads issued before compute, swizzled ds_write after).
// Grid (4, 2, 64) = 512 blocks.
// ---------------------------------------------------------------------------
__global__ __launch_bounds__(256, 3) void adj_k(
    const _Float16* __restrict__ axtc_r, const _Float16* __restrict__ axtc_i,
    const _Float16* __restrict__ aytc_r, const _Float16* __restrict__ aytc_i,
    const _Float16* __restrict__ kwh_r, const _Float16* __restrict__ kwh_i,
    float* __restrict__ out) {
  __shared__ _Float16 lds[2][12288];   // 48 KB

  const int t  = threadIdx.x;
  const int w  = t >> 6;
  const int l  = t & 63;
  const int lr = l & 15;
  const int q  = l >> 4;
  const int b  = blockIdx.z;
  const int i0 = blockIdx.x * 64;
  const int j0 = blockIdx.y * 128;

  const int srow   = l >> 2;
  const int schunk = (l & 3) ^ ((l >> 3) & 3);
  const int gA     = srow * M_ + schunk * 8;      // A row stride = 1920 halfs
  const int rc     = (q ^ ((lr >> 1) & 3)) << 3;

  // W staging: thread -> (j-row = t>>1, m-half = t&1); swizzled b128 writes
  const int wrow = t >> 1;
  const int wh   = t & 1;
  const int wp   = (wrow >> 1) & 3;
  const int wc0  = ((2 * wh + 0) ^ wp) << 3;
  const int wc1  = ((2 * wh + 1) ^ wp) << 3;

  const floatx4 z4 = {0.f, 0.f, 0.f, 0.f};
  floatx4 accr[4][2], acci[4][2];
#pragma unroll
  for (int mt = 0; mt < 4; ++mt)
#pragma unroll
    for (int jt = 0; jt < 2; ++jt) { accr[mt][jt] = z4; acci[mt][jt] = z4; }

  uint4 Yr0, Yr1, Yi0, Yi1, Cr0, Cr1, Ci0, Ci1;

  auto stageA = [&](int buf, int s) {
    const int mc = s * 32;
    _Float16* L = lds[buf];
    const size_t off = (size_t)(i0 + w * 16) * M_ + mc + gA;
    gll16(axtc_r + off, L + 0    + w * 512);
    gll16(axtc_i + off, L + 2048 + w * 512);
  };

  auto loadW = [&](int s) {   // issue early; consumed by writeW after compute
    const int mc = s * 32 + wh * 16;
    const size_t oy = (size_t)(j0 + wrow) * M_ + mc;
    const size_t oc = (size_t)b * M_ + mc;
    Yr0 = *(const uint4*)&aytc_r[oy];  Yr1 = *(const uint4*)&aytc_r[oy + 8];
    Yi0 = *(const uint4*)&aytc_i[oy];  Yi1 = *(const uint4*)&aytc_i[oy + 8];
    Cr0 = *(const uint4*)&kwh_r[oc];   Cr1 = *(const uint4*)&kwh_r[oc + 8];
    Ci0 = *(const uint4*)&kwh_i[oc];   Ci1 = *(const uint4*)&kwh_i[oc + 8];
  };

  auto writeW = [&](int buf) {
    __half2 Wr0[4], Wi0[4], Wr1[4], Wi1[4];
    {
      const __half2* yr = (const __half2*)&Yr0; const __half2* yi = (const __half2*)&Yi0;
      const __half2* cr = (const __half2*)&Cr0; const __half2* ci = (const __half2*)&Ci0;
#pragma unroll
      for (int e = 0; e < 4; ++e) {
        Wr0[e] = __hsub2(__hmul2(cr[e], yr[e]), __hmul2(ci[e], yi[e]));
        Wi0[e] = __hfma2(cr[e], yi[e], __hmul2(ci[e], yr[e]));
      }
    }
    {
      const __half2* yr = (const __half2*)&Yr1; const __half2* yi = (const __half2*)&Yi1;
      const __half2* cr = (const __half2*)&Cr1; const __half2* ci = (const __half2*)&Ci1;
#pragma unroll
      for (int e = 0; e < 4; ++e) {
        Wr1[e] = __hsub2(__hmul2(cr[e], yr[e]), __hmul2(ci[e], yi[e]));
        Wi1[e] = __hfma2(cr[e], yi[e], __hmul2(ci[e], yr[e]));
      }
    }
    _Float16* Lr = lds[buf] + 4096;
    _Float16* Li = lds[buf] + 8192;
    const int rb = wrow * 32;
    *(uint4*)&Lr[rb + wc0] = *(const uint4*)&Wr0[0];
    *(uint4*)&Lr[rb + wc1] = *(const uint4*)&Wr1[0];
    *(uint4*)&Li[rb + wc0] = *(const uint4*)&Wi0[0];
    *(uint4*)&Li[rb + wc1] = *(const uint4*)&Wi1[0];
  };

  auto compute = [&](int buf) {
    const _Float16* L = lds[buf];
    half8 br[2], bi[2], nbi[2];
#pragma unroll
    for (int jt = 0; jt < 2; ++jt) {
      const int ro = (w * 32 + jt * 16 + lr) * 32 + rc;
      br[jt]  = *(const half8*)&L[4096 + ro];
      bi[jt]  = *(const half8*)&L[8192 + ro];
      nbi[jt] = -bi[jt];
    }
#pragma unroll
    for (int mt = 0; mt < 4; ++mt) {
      const int ro = (mt * 16 + lr) * 32 + rc;
      half8 ar = *(const half8*)&L[0 + ro];
      half8 ai = *(const half8*)&L[2048 + ro];
#pragma unroll
      for (int jt = 0; jt < 2; ++jt) {
        accr[mt][jt] = __builtin_amdgcn_mfma_f32_16x16x32_f16(ar, br[jt],  accr[mt][jt], 0, 0, 0);
        accr[mt][jt] = __builtin_amdgcn_mfma_f32_16x16x32_f16(ai, nbi[jt], accr[mt][jt], 0, 0, 0);
        acci[mt][jt] = __builtin_amdgcn_mfma_f32_16x16x32_f16(ar, bi[jt],  acci[mt][jt], 0, 0, 0);
        acci[mt][jt] = __builtin_amdgcn_mfma_f32_16x16x32_f16(ai, br[jt],  acci[mt][jt], 0, 0, 0);
      }
    }
  };

  loadW(0);
  stageA(0, 0);
  writeW(0);
  __syncthreads();
#pragma unroll 2
  for (int s = 0; s < 60; ++s) {
    const int buf = s & 1;
    if (s < 59) { stageA(buf ^ 1, s + 1); loadW(s + 1); }
    compute(buf);
    if (s < 59) writeW(buf ^ 1);
    __syncthreads();
  }

  const float sc = 1.0f / (float)IMG2;
#pragma unroll
  for (int mt = 0; mt < 4; ++mt)
#pragma unroll
    for (int jt = 0; jt < 2; ++jt) {
      const int jg = j0 + w * 32 + jt * 16 + lr;
#pragma unroll
      for (int reg = 0; reg < 4; ++reg) {
        const int ig = i0 + mt * 16 + q * 4 + reg;
        float2 v = make_float2(accr[mt][jt][reg] * sc, acci[mt][jt][reg] * sc);
        *(float2*)&out[((size_t)(b * IMG_ + ig) * IMG_ + jg) * 2] = v;
      }
    }
}

// ---------------------------------------------------------------------------
// Launch
// ---------------------------------------------------------------------------
extern "C" void kernel_launch(void* const* d_in, const int* in_sizes, int n_in,
                              void* d_out, int out_size, void* d_ws, size_t ws_size,
                              hipStream_t stream) {
  (void)in_sizes; (void)n_in; (void)out_size; (void)ws_size;

  const float* xr      = (const float*)d_in[0];
  const float* xi      = (const float*)d_in[1];
  const float* samples = (const float*)d_in[2];
  const float* density = (const float*)d_in[3];
  float* out = (float*)d_out;

  // ws: 10 f16 arrays, 8.36 MB total
  _Float16* f = (_Float16*)d_ws;
  _Float16* axh_r  = f + 0 * MI_;
  _Float16* axh_i  = f + 1 * MI_;
  _Float16* ayh_r  = f + 2 * MI_;
  _Float16* ayh_i  = f + 3 * MI_;
  _Float16* axtc_r = f + 4 * MI_;
  _Float16* axtc_i = f + 5 * MI_;
  _Float16* aytc_r = f + 6 * MI_;
  _Float16* aytc_i = f + 7 * MI_;
  _Float16* kwh_r  = f + 8 * MI_;
  _Float16* kwh_i  = kwh_r + B_ * M_;

  // X^T (f16) parked in d_out; fully consumed by fwd_k before adj_k overwrites.
  _Float16* xth_r = (_Float16*)d_out;
  _Float16* xth_i = xth_r + (size_t)B_ * IMG2;

  phase1_k<<<(MI_ + 255) / 256, 256, 0, stream>>>(samples, axh_r, axh_i, ayh_r, ayh_i);
  phase2_k<<<dim3(8, IMG_), 256, 0, stream>>>(samples, axtc_r, axtc_i, aytc_r, aytc_i);
  xt_k<<<dim3(8, 8, B_), 256, 0, stream>>>(xr, xi, xth_r, xth_i);
  fwd_k<<<dim3(M_ / 64, B_), 256, 0, stream>>>(axh_r, axh_i, ayh_r, ayh_i,
                                               xth_r, xth_i, density, kwh_r, kwh_i);
  adj_k<<<dim3(4, 2, B_), 256, 0, stream>>>(axtc_r, axtc_i, aytc_r, aytc_i,
                                            kwh_r, kwh_i, out);
}

// Round 3
// 264.016 us; speedup vs baseline: 2.3505x; 1.2924x over previous
//
#include <hip/hip_runtime.h>
#include <hip/hip_bf16.h>
#include <hip/hip_fp16.h>

// Problem constants (match reference)
constexpr int IMG_ = 256;
constexpr int M_   = 1920;   // N_SHOTS * N_SAMPLES
constexpr int B_   = 64;
constexpr int MI_  = M_ * IMG_;          // 491520 elements per phase table
constexpr int IMG2 = IMG_ * IMG_;        // 65536

typedef _Float16 half8 __attribute__((ext_vector_type(8)));
typedef float    floatx4 __attribute__((ext_vector_type(4)));

// global -> LDS direct copy, 16B per lane; LDS dest is wave-uniform base + lane*16
__device__ __forceinline__ void gll16(const _Float16* g, _Float16* l) {
  __builtin_amdgcn_global_load_lds(
      (const __attribute__((address_space(1))) void*)g,
      (__attribute__((address_space(3))) void*)l, 16, 0, 0);
}

// ---------------------------------------------------------------------------
// Phase tables, natural layout [m][i] (f16): Ax = exp(-2i*pi*kx*g), Ay likewise
// ---------------------------------------------------------------------------
__global__ __launch_bounds__(256) void phase1_k(
    const float* __restrict__ samples,
    _Float16* __restrict__ axh_r, _Float16* __restrict__ axh_i,
    _Float16* __restrict__ ayh_r, _Float16* __restrict__ ayh_i) {
  int idx = blockIdx.x * 256 + threadIdx.x;
  if (idx >= MI_) return;
  int m = idx >> 8;
  int i = idx & 255;
  float g  = (float)i - 128.0f;
  float kx = samples[2 * m + 0];
  float ky = samples[2 * m + 1];
  float sx, cx, sy, cy;
  sincospif(-2.0f * kx * g, &sx, &cx);
  sincospif(-2.0f * ky * g, &sy, &cy);
  axh_r[idx] = (_Float16)cx; axh_i[idx] = (_Float16)sx;
  ayh_r[idx] = (_Float16)cy; ayh_i[idx] = (_Float16)sy;
}

// Transposed, pre-conjugated tables [i][m] (f16) for the adjoint pass.
__global__ __launch_bounds__(256) void phase2_k(
    const float* __restrict__ samples,
    _Float16* __restrict__ axtc_r, _Float16* __restrict__ axtc_i,
    _Float16* __restrict__ aytc_r, _Float16* __restrict__ aytc_i) {
  int m = blockIdx.x * 256 + threadIdx.x;
  if (m >= M_) return;
  int i = blockIdx.y;
  float g  = (float)i - 128.0f;
  float kx = samples[2 * m + 0];
  float ky = samples[2 * m + 1];
  float sx, cx, sy, cy;
  sincospif(-2.0f * kx * g, &sx, &cx);
  sincospif(-2.0f * ky * g, &sy, &cy);
  int o = i * M_ + m;
  axtc_r[o] = (_Float16)cx; axtc_i[o] = (_Float16)(-sx);  // conj(Ax)^T
  aytc_r[o] = (_Float16)cy; aytc_i[o] = (_Float16)(-sy);  // conj(Ay)^T
}

// ---------------------------------------------------------------------------
// X transpose + f16 convert: xth[b][j][i] = x[b][i][j]  (B-operand for fwd)
// ---------------------------------------------------------------------------
__global__ __launch_bounds__(256) void xt_k(
    const float* __restrict__ xr, const float* __restrict__ xi,
    _Float16* __restrict__ xth_r, _Float16* __restrict__ xth_i) {
  __shared__ float tr[32][33], ti[32][33];
  const int t = threadIdx.x;
  const int b = blockIdx.z;
  const int i0 = blockIdx.x * 32, j0 = blockIdx.y * 32;
  const int r = t >> 5, c = t & 31;
#pragma unroll
  for (int k = 0; k < 4; ++k) {
    int row = r + k * 8;
    tr[row][c] = xr[(size_t)b * IMG2 + (i0 + row) * IMG_ + j0 + c];
    ti[row][c] = xi[(size_t)b * IMG2 + (i0 + row) * IMG_ + j0 + c];
  }
  __syncthreads();
#pragma unroll
  for (int k = 0; k < 4; ++k) {
    int row = r + k * 8;
    xth_r[(size_t)b * IMG2 + (j0 + row) * IMG_ + i0 + c] = (_Float16)tr[c][row];
    xth_i[(size_t)b * IMG2 + (j0 + row) * IMG_ + i0 + c] = (_Float16)ti[c][row];
  }
}

// ---------------------------------------------------------------------------
// LDS layout (both GEMM kernels), per 32-half (64B) row of 4 16B chunks:
// physical chunk p of row r holds logical chunk p ^ ((r>>1)&3).
//  - staging via global_load_lds: HW writes lane-linear (lane l -> row l>>2,
//    phys chunk l&3); lane fetches global logical chunk (l&3)^((l>>3)&3).
//  - ds_read_b128 frags read phys chunk q ^ ((lr>>1)&3): zero bank conflicts
//    (measured rounds 1-2: SQ_LDS_BANK_CONFLICT = 0).
// Regions (halfs): A_r 0..2048, A_i 2048..4096, B_r 4096..8192, B_i 8192..12288
// per buffer (24 KB); x2 double-buffer = 48 KB -> 3 blocks/CU.
// ---------------------------------------------------------------------------

// ---------------------------------------------------------------------------
// Forward NDFT via f16 MFMA + fused Ay-weighted j-reduction.
//   kpart[jc][b][m] = sum_{j in jc half} Ay[m,j] * (sum_i Ax[m,i] * X_b[i,j])
// Block: 256 thr = 4 waves; block tile 64m x 128j (one jc half), 8 k-steps;
// wave tile 64m x 32j (acc 64 VGPR). Epilogue ONCE after the loop -> no
// mid-loop register pressure (round-2 spill fix).
// 1-D grid 3840, XCD-grouped: block n -> XCD n%8 (HW round-robin); decode so
// each XCD processes whole b-groups consecutively -> X_b + tables L2-resident.
// ---------------------------------------------------------------------------
__global__ __launch_bounds__(256, 3) void fwd_k(
    const _Float16* __restrict__ axh_r, const _Float16* __restrict__ axh_i,
    const _Float16* __restrict__ ayh_r, const _Float16* __restrict__ ayh_i,
    const _Float16* __restrict__ xth_r, const _Float16* __restrict__ xth_i,
    float2* __restrict__ kpart) {
  __shared__ _Float16 lds[2][12288];   // 48 KB

  const int t  = threadIdx.x;
  const int w  = t >> 6;
  const int l  = t & 63;
  const int lr = l & 15;   // frag row within 16-tile; C col (j)
  const int q  = l >> 4;   // k-chunk; C row group (m)

  // XCD-grouped decode: xcd = n&7; b-group fixed over 60 consecutive r
  const int n     = blockIdx.x;        // 0..3839
  const int r     = n >> 3;            // 0..479
  const int b     = (n & 7) + 8 * (r / 60);
  const int inner = r % 60;
  const int m0    = (inner % 30) * 64;
  const int jc    = inner / 30;
  const int j0    = jc * 128;

  const int srow   = l >> 2;                      // staging row within 16
  const int schunk = (l & 3) ^ ((l >> 3) & 3);    // pre-swizzled global chunk
  const int gA     = srow * IMG_ + schunk * 8;    // halfs
  const int rc     = (q ^ ((lr >> 1) & 3)) << 3;  // frag-read swizzled chunk

  const floatx4 z4 = {0.f, 0.f, 0.f, 0.f};
  floatx4 accr[4][2], acci[4][2];
#pragma unroll
  for (int mt = 0; mt < 4; ++mt)
#pragma unroll
    for (int jt = 0; jt < 2; ++jt) { accr[mt][jt] = z4; acci[mt][jt] = z4; }

  auto stage = [&](int buf, int s) {
    const int col = s * 32;
    _Float16* L = lds[buf];
    const size_t offA = (size_t)(m0 + w * 16) * IMG_ + col + gA;
    gll16(axh_r + offA, L + 0    + w * 512);
    gll16(axh_i + offA, L + 2048 + w * 512);
    const size_t offB = (size_t)b * IMG2 + (size_t)(j0 + w * 32) * IMG_ + col + gA;
    gll16(xth_r + offB,             L + 4096 + w * 1024);
    gll16(xth_r + offB + 16 * IMG_, L + 4096 + w * 1024 + 512);
    gll16(xth_i + offB,             L + 8192 + w * 1024);
    gll16(xth_i + offB + 16 * IMG_, L + 8192 + w * 1024 + 512);
  };

  auto compute = [&](int buf) {
    const _Float16* L = lds[buf];
    half8 br[2], bi[2], nbi[2];
#pragma unroll
    for (int jt = 0; jt < 2; ++jt) {
      const int ro = (w * 32 + jt * 16 + lr) * 32 + rc;
      br[jt]  = *(const half8*)&L[4096 + ro];
      bi[jt]  = *(const half8*)&L[8192 + ro];
      nbi[jt] = -bi[jt];
    }
#pragma unroll
    for (int mt = 0; mt < 4; ++mt) {
      const int ro = (mt * 16 + lr) * 32 + rc;
      half8 ar = *(const half8*)&L[0 + ro];
      half8 ai = *(const half8*)&L[2048 + ro];
#pragma unroll
      for (int jt = 0; jt < 2; ++jt) {
        accr[mt][jt] = __builtin_amdgcn_mfma_f32_16x16x32_f16(ar, br[jt],  accr[mt][jt], 0, 0, 0);
        accr[mt][jt] = __builtin_amdgcn_mfma_f32_16x16x32_f16(ai, nbi[jt], accr[mt][jt], 0, 0, 0);
        acci[mt][jt] = __builtin_amdgcn_mfma_f32_16x16x32_f16(ar, bi[jt],  acci[mt][jt], 0, 0, 0);
        acci[mt][jt] = __builtin_amdgcn_mfma_f32_16x16x32_f16(ai, br[jt],  acci[mt][jt], 0, 0, 0);
      }
    }
  };

  stage(0, 0);
  __syncthreads();               // implicit vmcnt(0) drains global_load_lds
#pragma unroll
  for (int s = 0; s < 8; ++s) {
    const int buf = s & 1;
    if (s < 7) stage(buf ^ 1, s + 1);    // next-tile loads overlap MFMA
    compute(buf);
    __syncthreads();
  }

  // Epilogue (once, post-loop): kacc[m] += sum_j Ay[m,j]*T[m,j]
  // (C layout: col=lr -> j, row=q*4+reg -> m)
  float kr[4][4] = {}, ki[4][4] = {};
#pragma unroll
  for (int mt = 0; mt < 4; ++mt)
#pragma unroll
    for (int jt = 0; jt < 2; ++jt) {
      const int j = j0 + w * 32 + jt * 16 + lr;
#pragma unroll
      for (int reg = 0; reg < 4; ++reg) {
        const int m = m0 + mt * 16 + q * 4 + reg;
        const float yr = (float)ayh_r[m * IMG_ + j];
        const float yi = (float)ayh_i[m * IMG_ + j];
        const float tr = accr[mt][jt][reg], ti = acci[mt][jt][reg];
        kr[mt][reg] = fmaf(yr, tr, fmaf(-yi, ti, kr[mt][reg]));
        ki[mt][reg] = fmaf(yr, ti, fmaf(yi, tr, ki[mt][reg]));
      }
    }

  // reduce over the 16 j-lanes of each row group
#pragma unroll
  for (int mt = 0; mt < 4; ++mt)
#pragma unroll
    for (int reg = 0; reg < 4; ++reg)
#pragma unroll
      for (int off = 1; off < 16; off <<= 1) {
        kr[mt][reg] += __shfl_xor(kr[mt][reg], off);
        ki[mt][reg] += __shfl_xor(ki[mt][reg], off);
      }

  // cross-wave combine (4 j-slices) via LDS scratch; write f32 partial
  float2* scr = (float2*)&lds[0][0];
  if (lr == 0) {
#pragma unroll
    for (int mt = 0; mt < 4; ++mt)
#pragma unroll
      for (int reg = 0; reg < 4; ++reg)
        scr[w * 64 + mt * 16 + q * 4 + reg] = make_float2(kr[mt][reg], ki[mt][reg]);
  }
  __syncthreads();
  if (t < 64) {
    float sr = 0.f, si = 0.f;
#pragma unroll
    for (int ww = 0; ww < 4; ++ww) {
      const float2 p = scr[ww * 64 + t];
      sr += p.x; si += p.y;
    }
    kpart[((size_t)jc * B_ + b) * M_ + m0 + t] = make_float2(sr, si);
  }
}

// ---------------------------------------------------------------------------
// Combine jc partials, apply density, convert to f16 kw.
// ---------------------------------------------------------------------------
__global__ __launch_bounds__(256) void comb_k(
    const float2* __restrict__ kpart, const float* __restrict__ density,
    _Float16* __restrict__ kwh_r, _Float16* __restrict__ kwh_i) {
  const int idx = blockIdx.x * 256 + threadIdx.x;
  if (idx >= B_ * M_) return;
  const int m = idx % M_;
  const float2 p0 = kpart[idx];
  const float2 p1 = kpart[(size_t)B_ * M_ + idx];
  const float d = density[m];
  kwh_r[idx] = (_Float16)((p0.x + p1.x) * d);
  kwh_i[idx] = (_Float16)((p0.y + p1.y) * d);
}

// ---------------------------------------------------------------------------
// Adjoint NDFT via f16 MFMA:
//   out[b,i,j] = (1/IMG^2) sum_m conj(Ax)[m,i] * kw[b,m] * conj(Ay)[m,j]
// Block: 256 thr = 4 waves; block tile 64i x 128j (wave w owns j-slice w*32);
// wave tile 64i x 32j -> acc 64 VGPR. K = 1920 m, 60 steps, double-buffered.
// 1-D grid 512, XCD-grouped: XCD x owns one (i0,j0) combo for all 64 b ->
// axtc/aytc strips (~1.5 MB) L2-resident per XCD.
// ---------------------------------------------------------------------------
__global__ __launch_bounds__(256, 3) void adj_k(
    const _Float16* __restrict__ axtc_r, const _Float16* __restrict__ axtc_i,
    const _Float16* __restrict__ aytc_r, const _Float16* __restrict__ aytc_i,
    const _Float16* __restrict__ kwh_r, const _Float16* __restrict__ kwh_i,
    float* __restrict__ out) {
  __shared__ _Float16 lds[2][12288];   // 48 KB

  const int t  = threadIdx.x;
  const int w  = t >> 6;
  const int l  = t & 63;
  const int lr = l & 15;
  const int q  = l >> 4;

  const int n     = blockIdx.x;         // 0..511
  const int combo = n & 7;              // -> XCD
  const int b     = n >> 3;
  const int i0    = (combo >> 1) * 64;
  const int j0    = (combo & 1) * 128;

  const int srow   = l >> 2;
  const int schunk = (l & 3) ^ ((l >> 3) & 3);
  const int gA     = srow * M_ + schunk * 8;      // A row stride = 1920 halfs
  const int rc     = (q ^ ((lr >> 1) & 3)) << 3;

  // W staging: thread -> (j-row = t>>1, m-half = t&1); swizzled b128 writes
  const int wrow = t >> 1;
  const int wh   = t & 1;
  const int wp   = (wrow >> 1) & 3;
  const int wc0  = ((2 * wh + 0) ^ wp) << 3;
  const int wc1  = ((2 * wh + 1) ^ wp) << 3;

  const floatx4 z4 = {0.f, 0.f, 0.f, 0.f};
  floatx4 accr[4][2], acci[4][2];
#pragma unroll
  for (int mt = 0; mt < 4; ++mt)
#pragma unroll
    for (int jt = 0; jt < 2; ++jt) { accr[mt][jt] = z4; acci[mt][jt] = z4; }

  uint4 Yr0, Yr1, Yi0, Yi1, Cr0, Cr1, Ci0, Ci1;

  auto stageA = [&](int buf, int s) {
    const int mc = s * 32;
    _Float16* L = lds[buf];
    const size_t off = (size_t)(i0 + w * 16) * M_ + mc + gA;
    gll16(axtc_r + off, L + 0    + w * 512);
    gll16(axtc_i + off, L + 2048 + w * 512);
  };

  auto loadW = [&](int s) {   // issue early; consumed by writeW after compute
    const int mc = s * 32 + wh * 16;
    const size_t oy = (size_t)(j0 + wrow) * M_ + mc;
    const size_t oc = (size_t)b * M_ + mc;
    Yr0 = *(const uint4*)&aytc_r[oy];  Yr1 = *(const uint4*)&aytc_r[oy + 8];
    Yi0 = *(const uint4*)&aytc_i[oy];  Yi1 = *(const uint4*)&aytc_i[oy + 8];
    Cr0 = *(const uint4*)&kwh_r[oc];   Cr1 = *(const uint4*)&kwh_r[oc + 8];
    Ci0 = *(const uint4*)&kwh_i[oc];   Ci1 = *(const uint4*)&kwh_i[oc + 8];
  };

  auto writeW = [&](int buf) {
    __half2 Wr0[4], Wi0[4], Wr1[4], Wi1[4];
    {
      const __half2* yr = (const __half2*)&Yr0; const __half2* yi = (const __half2*)&Yi0;
      const __half2* cr = (const __half2*)&Cr0; const __half2* ci = (const __half2*)&Ci0;
#pragma unroll
      for (int e = 0; e < 4; ++e) {
        Wr0[e] = __hsub2(__hmul2(cr[e], yr[e]), __hmul2(ci[e], yi[e]));
        Wi0[e] = __hfma2(cr[e], yi[e], __hmul2(ci[e], yr[e]));
      }
    }
    {
      const __half2* yr = (const __half2*)&Yr1; const __half2* yi = (const __half2*)&Yi1;
      const __half2* cr = (const __half2*)&Cr1; const __half2* ci = (const __half2*)&Ci1;
#pragma unroll
      for (int e = 0; e < 4; ++e) {
        Wr1[e] = __hsub2(__hmul2(cr[e], yr[e]), __hmul2(ci[e], yi[e]));
        Wi1[e] = __hfma2(cr[e], yi[e], __hmul2(ci[e], yr[e]));
      }
    }
    _Float16* Lr = lds[buf] + 4096;
    _Float16* Li = lds[buf] + 8192;
    const int rb = wrow * 32;
    *(uint4*)&Lr[rb + wc0] = *(const uint4*)&Wr0[0];
    *(uint4*)&Lr[rb + wc1] = *(const uint4*)&Wr1[0];
    *(uint4*)&Li[rb + wc0] = *(const uint4*)&Wi0[0];
    *(uint4*)&Li[rb + wc1] = *(const uint4*)&Wi1[0];
  };

  auto compute = [&](int buf) {
    const _Float16* L = lds[buf];
    half8 br[2], bi[2], nbi[2];
#pragma unroll
    for (int jt = 0; jt < 2; ++jt) {
      const int ro = (w * 32 + jt * 16 + lr) * 32 + rc;
      br[jt]  = *(const half8*)&L[4096 + ro];
      bi[jt]  = *(const half8*)&L[8192 + ro];
      nbi[jt] = -bi[jt];
    }
#pragma unroll
    for (int mt = 0; mt < 4; ++mt) {
      const int ro = (mt * 16 + lr) * 32 + rc;
      half8 ar = *(const half8*)&L[0 + ro];
      half8 ai = *(const half8*)&L[2048 + ro];
#pragma unroll
      for (int jt = 0; jt < 2; ++jt) {
        accr[mt][jt] = __builtin_amdgcn_mfma_f32_16x16x32_f16(ar, br[jt],  accr[mt][jt], 0, 0, 0);
        accr[mt][jt] = __builtin_amdgcn_mfma_f32_16x16x32_f16(ai, nbi[jt], accr[mt][jt], 0, 0, 0);
        acci[mt][jt] = __builtin_amdgcn_mfma_f32_16x16x32_f16(ar, bi[jt],  acci[mt][jt], 0, 0, 0);
        acci[mt][jt] = __builtin_amdgcn_mfma_f32_16x16x32_f16(ai, br[jt],  acci[mt][jt], 0, 0, 0);
      }
    }
  };

  loadW(0);
  stageA(0, 0);
  writeW(0);
  __syncthreads();
#pragma unroll 2
  for (int s = 0; s < 60; ++s) {
    const int buf = s & 1;
    if (s < 59) { stageA(buf ^ 1, s + 1); loadW(s + 1); }
    compute(buf);
    if (s < 59) writeW(buf ^ 1);
    __syncthreads();
  }

  const float sc = 1.0f / (float)IMG2;
#pragma unroll
  for (int mt = 0; mt < 4; ++mt)
#pragma unroll
    for (int jt = 0; jt < 2; ++jt) {
      const int jg = j0 + w * 32 + jt * 16 + lr;
#pragma unroll
      for (int reg = 0; reg < 4; ++reg) {
        const int ig = i0 + mt * 16 + q * 4 + reg;
        float2 v = make_float2(accr[mt][jt][reg] * sc, acci[mt][jt][reg] * sc);
        *(float2*)&out[((size_t)(b * IMG_ + ig) * IMG_ + jg) * 2] = v;
      }
    }
}

// ---------------------------------------------------------------------------
// Launch
// ---------------------------------------------------------------------------
extern "C" void kernel_launch(void* const* d_in, const int* in_sizes, int n_in,
                              void* d_out, int out_size, void* d_ws, size_t ws_size,
                              hipStream_t stream) {
  (void)in_sizes; (void)n_in; (void)out_size; (void)ws_size;

  const float* xr      = (const float*)d_in[0];
  const float* xi      = (const float*)d_in[1];
  const float* samples = (const float*)d_in[2];
  const float* density = (const float*)d_in[3];
  float* out = (float*)d_out;

  // ws: 10 f16 arrays, 8.36 MB total
  _Float16* f = (_Float16*)d_ws;
  _Float16* axh_r  = f + 0 * MI_;
  _Float16* axh_i  = f + 1 * MI_;
  _Float16* ayh_r  = f + 2 * MI_;
  _Float16* ayh_i  = f + 3 * MI_;
  _Float16* axtc_r = f + 4 * MI_;
  _Float16* axtc_i = f + 5 * MI_;
  _Float16* aytc_r = f + 6 * MI_;
  _Float16* aytc_i = f + 7 * MI_;
  _Float16* kwh_r  = f + 8 * MI_;
  _Float16* kwh_i  = kwh_r + B_ * M_;

  // d_out parking (33.5 MB total):
  //  [0, 16.7 MB): X^T f16 (consumed by fwd_k)
  //  [16.7, 18.7 MB): kpart f32 partials (consumed by comb_k)
  // adj_k overwrites the whole buffer afterwards.
  _Float16* xth_r = (_Float16*)d_out;
  _Float16* xth_i = xth_r + (size_t)B_ * IMG2;
  float2*   kpart = (float2*)(xth_i + (size_t)B_ * IMG2);

  phase1_k<<<(MI_ + 255) / 256, 256, 0, stream>>>(samples, axh_r, axh_i, ayh_r, ayh_i);
  phase2_k<<<dim3(8, IMG_), 256, 0, stream>>>(samples, axtc_r, axtc_i, aytc_r, aytc_i);
  xt_k<<<dim3(8, 8, B_), 256, 0, stream>>>(xr, xi, xth_r, xth_i);
  fwd_k<<<3840, 256, 0, stream>>>(axh_r, axh_i, ayh_r, ayh_i, xth_r, xth_i, kpart);
  comb_k<<<(B_ * M_ + 255) / 256, 256, 0, stream>>>(kpart, density, kwh_r, kwh_i);
  adj_k<<<512, 256, 0, stream>>>(axtc_r, axtc_i, aytc_r, aytc_i, kwh_r, kwh_i, out);
}